// Round 2
// baseline (5415.885 us; speedup 1.0000x reference)
//
#include <hip/hip_runtime.h>
#include <cstdint>
#include <cstddef>

// Attention_41231686042092: ViT attention + softmax sparsification (per-(b,h)
// exact median threshold via radix select on f32 bit patterns) + diag-based
// token pruning + projection. All f32 (ranking needs exact-index fidelity).
//
// Two workspace layouts chosen at launch from ws_size (deterministic):
//  BIG  (~356 MiB): store full attn; refine/AV read it back (L2/L3 resident).
//  SMALL (~113 MiB): never store attn; stats pass + 2 refine passes + AV all
//    recompute QK^T with a bit-identical fmaf chain (dot4) so the selection,
//    masking, and ranking decisions are self-consistent across kernels.

namespace {
constexpr int B_  = 16;
constexpr int N_  = 577;
constexpr int C_  = 768;
constexpr int H_  = 12;
constexpr int HD_ = 64;
constexpr int BH_ = B_ * H_;            // 192
constexpr int KK_ = N_ - 57;            // 520 kept tokens
constexpr long long NN2 = (long long)N_ * N_;   // 332929
constexpr unsigned KIDX_ = 166464u;     // int(N*N*0.5), 0-based desc rank
constexpr int M1_ = B_ * N_;            // 9232
constexpr int M2_ = B_ * KK_;           // 8320
}

// Shared exact dot: 4 independent sequential fmaf chains over d=0..63.
// Used by ALL small-path QK kernels => bit-identical logits everywhere.
__device__ __forceinline__ void dot4(const float* __restrict__ q,
                                     const float* __restrict__ k0,
                                     const float* __restrict__ k1,
                                     const float* __restrict__ k2,
                                     const float* __restrict__ k3,
                                     float l[4]) {
  l[0] = l[1] = l[2] = l[3] = 0.f;
#pragma unroll
  for (int d = 0; d < 64; d++) {
    float qa = q[d];
    l[0] = __builtin_fmaf(qa, k0[d], l[0]);
    l[1] = __builtin_fmaf(qa, k1[d], l[1]);
    l[2] = __builtin_fmaf(qa, k2[d], l[2]);
    l[3] = __builtin_fmaf(qa, k3[d], l[3]);
  }
}

// ---------------------------------------------------------------- QKV GEMM
__global__ __launch_bounds__(256) void qkv_gemm(
    const float* __restrict__ X, const float* __restrict__ W,
    float* __restrict__ qb, float* __restrict__ kb, float* __restrict__ vb) {
  __shared__ float Xs[16][65];
  __shared__ float Ws[16][65];
  const int m0 = blockIdx.x * 64;
  const int n0 = blockIdx.y * 64;
  const int t = threadIdx.x;
  const int tx = t & 15, ty = t >> 4;
  float acc[4][4] = {};
  for (int k0 = 0; k0 < 768; k0 += 16) {
    for (int i = 0; i < 4; i++) {
      int e = t + i * 256;
      int kk = e & 15, mm = e >> 4;
      int gm = m0 + mm;
      Xs[kk][mm] = (gm < M1_) ? X[(size_t)gm * 768 + k0 + kk] : 0.f;
      Ws[kk][mm] = W[(size_t)(n0 + mm) * 768 + k0 + kk];
    }
    __syncthreads();
#pragma unroll
    for (int kk = 0; kk < 16; kk++) {
      float a[4], bb[4];
#pragma unroll
      for (int i = 0; i < 4; i++) a[i] = Xs[kk][tx + 16 * i];
#pragma unroll
      for (int j = 0; j < 4; j++) bb[j] = Ws[kk][ty + 16 * j];
#pragma unroll
      for (int i = 0; i < 4; i++)
#pragma unroll
        for (int j = 0; j < 4; j++) acc[i][j] += a[i] * bb[j];
    }
    __syncthreads();
  }
  for (int i = 0; i < 4; i++) {
    int gm = m0 + tx + 16 * i;
    if (gm >= M1_) continue;
    int b = gm / N_, n = gm % N_;
    for (int j = 0; j < 4; j++) {
      int gn = n0 + ty + 16 * j;
      int which = gn / C_;
      int rem = gn % C_;
      int h = rem >> 6, d = rem & 63;
      float* dst = (which == 0) ? qb : (which == 1) ? kb : vb;
      dst[(((size_t)(b * H_ + h)) * N_ + n) * HD_ + d] = acc[i][j];
    }
  }
}

// ========================= BIG PATH (stored attn) =========================
__global__ __launch_bounds__(256) void attn_kernel(
    const float* __restrict__ qb, const float* __restrict__ kb,
    float* __restrict__ attn, float* __restrict__ diag,
    unsigned* __restrict__ hist1) {
  const int bh = blockIdx.x;
  const int q0 = blockIdx.y * 16;
  const int t = threadIdx.x;
  __shared__ float Qs[16][65];
  __shared__ float Ks[64][65];
  __shared__ float Lg[16][584];
  __shared__ float red[16][17];
  __shared__ unsigned hloc[4096];

  for (int i = t; i < 4096; i += 256) hloc[i] = 0u;
  {
    int r = t >> 4, d4 = (t & 15) * 4;
    int gq = q0 + r;
    float4 v = make_float4(0.f, 0.f, 0.f, 0.f);
    if (gq < N_) v = *(const float4*)&qb[((size_t)bh * N_ + gq) * HD_ + d4];
    Qs[r][d4 + 0] = v.x * 0.125f;
    Qs[r][d4 + 1] = v.y * 0.125f;
    Qs[r][d4 + 2] = v.z * 0.125f;
    Qs[r][d4 + 3] = v.w * 0.125f;
  }
  const int tx = t & 31, ty = t >> 5;
  for (int n0 = 0; n0 < N_; n0 += 64) {
    __syncthreads();
    {
      int nn = t >> 2;
      int gn = n0 + nn;
      for (int i = 0; i < 4; i++) {
        int d = ((t & 3) + 4 * i) * 4;
        float4 v = make_float4(0.f, 0.f, 0.f, 0.f);
        if (gn < N_) v = *(const float4*)&kb[((size_t)bh * N_ + gn) * HD_ + d];
        Ks[nn][d + 0] = v.x; Ks[nn][d + 1] = v.y;
        Ks[nn][d + 2] = v.z; Ks[nn][d + 3] = v.w;
      }
    }
    __syncthreads();
    float l00 = 0.f, l01 = 0.f, l10 = 0.f, l11 = 0.f;
#pragma unroll 8
    for (int d = 0; d < 64; d++) {
      float qa = Qs[ty][d], qc = Qs[ty + 8][d];
      float ka = Ks[tx][d], kc = Ks[tx + 32][d];
      l00 += qa * ka; l01 += qa * kc;
      l10 += qc * ka; l11 += qc * kc;
    }
    if (n0 + tx < N_)      { Lg[ty][n0 + tx]      = l00; Lg[ty + 8][n0 + tx]      = l10; }
    if (n0 + tx + 32 < N_) { Lg[ty][n0 + tx + 32] = l01; Lg[ty + 8][n0 + tx + 32] = l11; }
  }
  __syncthreads();

  const int rows = min(16, N_ - q0);
  const int rr = t >> 4, l16 = t & 15;
  {
    float mx = -1e30f;
    for (int m = l16; m < N_; m += 16) mx = fmaxf(mx, Lg[rr][m]);
    red[rr][l16] = mx;
  }
  __syncthreads();
  if (l16 == 0) {
    float mx = red[rr][0];
    for (int i = 1; i < 16; i++) mx = fmaxf(mx, red[rr][i]);
    red[rr][16] = mx;
  }
  __syncthreads();
  {
    float rowmax = red[rr][16];
    float s = 0.f;
    for (int m = l16; m < N_; m += 16) {
      float e = expf(Lg[rr][m] - rowmax);
      Lg[rr][m] = e;
      s += e;
    }
    __syncthreads();
    red[rr][l16] = s;
  }
  __syncthreads();
  if (l16 == 0) {
    float s = 0.f;
    for (int i = 0; i < 16; i++) s += red[rr][i];
    red[rr][16] = s;
  }
  __syncthreads();
  for (int r = 0; r < rows; r++) {
    float inv = 1.f / red[r][16];
    int gq = q0 + r;
    float* arow = attn + (size_t)bh * NN2 + (size_t)gq * N_;
    for (int m = t; m < N_; m += 256) {
      float val = Lg[r][m] * inv;
      arow[m] = val;
      atomicAdd(&hloc[__float_as_uint(val) >> 20], 1u);
      if (m == gq && gq > 0) diag[(size_t)bh * (N_ - 1) + gq - 1] = val;
    }
  }
  __syncthreads();
  for (int i = t; i < 4096; i += 256)
    if (hloc[i]) atomicAdd(&hist1[(size_t)bh * 4096 + i], hloc[i]);
}

__global__ __launch_bounds__(256) void hist_l2(
    const float* __restrict__ attn, const unsigned* __restrict__ pfx1,
    unsigned* __restrict__ hist2) {
  const int bh = blockIdx.x;
  __shared__ unsigned hloc[4096];
  for (int i = threadIdx.x; i < 4096; i += 256) hloc[i] = 0u;
  __syncthreads();
  const unsigned p = pfx1[bh];
  const float* base = attn + (size_t)bh * NN2;
  int start = blockIdx.y * 8192;
  int end = min(start + 8192, (int)NN2);
  for (int i = start + (int)threadIdx.x; i < end; i += 256) {
    unsigned bits = __float_as_uint(base[i]);
    if ((bits >> 20) == p) atomicAdd(&hloc[(bits >> 8) & 0xFFFu], 1u);
  }
  __syncthreads();
  for (int i = threadIdx.x; i < 4096; i += 256)
    if (hloc[i]) atomicAdd(&hist2[(size_t)bh * 4096 + i], hloc[i]);
}

__global__ __launch_bounds__(256) void hist_l3(
    const float* __restrict__ attn, const unsigned* __restrict__ pfx2,
    unsigned* __restrict__ hist3) {
  const int bh = blockIdx.x;
  __shared__ unsigned hloc[256];
  if (threadIdx.x < 256) hloc[threadIdx.x] = 0u;
  __syncthreads();
  const unsigned p = pfx2[bh];
  const float* base = attn + (size_t)bh * NN2;
  int start = blockIdx.y * 8192;
  int end = min(start + 8192, (int)NN2);
  for (int i = start + (int)threadIdx.x; i < end; i += 256) {
    unsigned bits = __float_as_uint(base[i]);
    if ((bits >> 8) == p) atomicAdd(&hloc[bits & 0xFFu], 1u);
  }
  __syncthreads();
  if (threadIdx.x < 256 && hloc[threadIdx.x])
    atomicAdd(&hist3[(size_t)bh * 256 + threadIdx.x], hloc[threadIdx.x]);
}

__global__ __launch_bounds__(256) void av_gemm(
    const float* __restrict__ attn, const float* __restrict__ vb,
    const int* __restrict__ kept, const unsigned* __restrict__ sigbits,
    float* __restrict__ out1) {
  const int bh = blockIdx.x;
  const int p0 = blockIdx.y * 32;
  const int b = bh / H_, h = bh % H_;
  const float sigma = __uint_as_float(sigbits[bh]);
  __shared__ float As[32][33];
  __shared__ float Vs[32][65];
  __shared__ int rowidx[32];
  const int t = threadIdx.x;
  if (t < 32) rowidx[t] = (p0 + t < KK_) ? kept[b * KK_ + p0 + t] : 0;
  const int tx = t & 15, ty = t >> 4;
  float acc[2][4] = {};
  for (int n0 = 0; n0 < N_; n0 += 32) {
    __syncthreads();
    {
      int pp = t >> 3;
      bool vp = (p0 + pp < KK_);
      const float* arow = attn + (size_t)bh * NN2 + (size_t)rowidx[pp] * N_;
      for (int j = 0; j < 4; j++) {
        int nn = (t & 7) * 4 + j;
        int gn = n0 + nn;
        float v = 0.f;
        if (vp && gn < N_) { float a = arow[gn]; v = (a >= sigma) ? a : 0.f; }
        As[pp][nn] = v;
      }
      int nn = t >> 3;
      int gn = n0 + nn;
      for (int j = 0; j < 8; j++) {
        int d = (t & 7) + 8 * j;
        Vs[nn][d] = (gn < N_) ? vb[((size_t)bh * N_ + gn) * HD_ + d] : 0.f;
      }
    }
    __syncthreads();
#pragma unroll
    for (int nn = 0; nn < 32; nn++) {
      float a0 = As[2 * ty][nn], a1 = As[2 * ty + 1][nn];
#pragma unroll
      for (int j = 0; j < 4; j++) {
        float vv = Vs[nn][tx + 16 * j];
        acc[0][j] += a0 * vv;
        acc[1][j] += a1 * vv;
      }
    }
  }
  for (int i = 0; i < 2; i++) {
    int p = p0 + 2 * ty + i;
    if (p >= KK_) continue;
    for (int j = 0; j < 4; j++) {
      int d = tx + 16 * j;
      out1[((size_t)(b * KK_ + p)) * C_ + h * HD_ + d] = acc[i][j];
    }
  }
}

// ======================= SMALL PATH (recompute attn) =======================
// Stats pass: logits -> rowmax/rowsum/diag + fused 12-bit histogram.
__global__ __launch_bounds__(256) void attn_stats(
    const float* __restrict__ qb, const float* __restrict__ kb,
    float* __restrict__ rowmax_g, float* __restrict__ rowsum_g,
    float* __restrict__ diag, unsigned* __restrict__ hist1) {
  const int bh = blockIdx.x;
  const int q0 = blockIdx.y * 16;
  const int t = threadIdx.x;
  __shared__ float Qs[16][65];
  __shared__ float Ks[64][65];
  __shared__ float Lg[16][584];
  __shared__ float red[16][17];
  __shared__ unsigned hloc[4096];

  for (int i = t; i < 4096; i += 256) hloc[i] = 0u;
  {
    int r = t >> 4, d4 = (t & 15) * 4;
    int gq = q0 + r;
    float4 v = make_float4(0.f, 0.f, 0.f, 0.f);
    if (gq < N_) v = *(const float4*)&qb[((size_t)bh * N_ + gq) * HD_ + d4];
    Qs[r][d4 + 0] = v.x * 0.125f;
    Qs[r][d4 + 1] = v.y * 0.125f;
    Qs[r][d4 + 2] = v.z * 0.125f;
    Qs[r][d4 + 3] = v.w * 0.125f;
  }
  const int row = t >> 4, kc = (t & 15) * 4;
  for (int n0 = 0; n0 < N_; n0 += 64) {
    __syncthreads();
    {
      int nn = t >> 2;
      int gn = n0 + nn;
      for (int i = 0; i < 4; i++) {
        int d = ((t & 3) + 4 * i) * 4;
        float4 v = make_float4(0.f, 0.f, 0.f, 0.f);
        if (gn < N_) v = *(const float4*)&kb[((size_t)bh * N_ + gn) * HD_ + d];
        Ks[nn][d + 0] = v.x; Ks[nn][d + 1] = v.y;
        Ks[nn][d + 2] = v.z; Ks[nn][d + 3] = v.w;
      }
    }
    __syncthreads();
    float l[4];
    dot4(&Qs[row][0], &Ks[kc][0], &Ks[kc + 1][0], &Ks[kc + 2][0], &Ks[kc + 3][0], l);
#pragma unroll
    for (int j = 0; j < 4; j++) {
      int gm = n0 + kc + j;
      if (gm < N_) Lg[row][gm] = l[j];
    }
  }
  __syncthreads();

  const int rows = min(16, N_ - q0);
  const int rr = t >> 4, l16 = t & 15;
  {
    float mx = -1e30f;
    for (int m = l16; m < N_; m += 16) mx = fmaxf(mx, Lg[rr][m]);
    red[rr][l16] = mx;
  }
  __syncthreads();
  if (l16 == 0) {
    float mx = red[rr][0];
    for (int i = 1; i < 16; i++) mx = fmaxf(mx, red[rr][i]);
    red[rr][16] = mx;
    if (q0 + rr < N_) rowmax_g[(size_t)bh * N_ + q0 + rr] = mx;
  }
  __syncthreads();
  {
    float rm = red[rr][16];
    float s = 0.f;
    for (int m = l16; m < N_; m += 16) {
      float e = expf(Lg[rr][m] - rm);
      Lg[rr][m] = e;
      s += e;
    }
    __syncthreads();
    red[rr][l16] = s;
  }
  __syncthreads();
  if (l16 == 0) {
    float s = 0.f;
    for (int i = 0; i < 16; i++) s += red[rr][i];
    red[rr][16] = s;
    if (q0 + rr < N_) rowsum_g[(size_t)bh * N_ + q0 + rr] = s;
  }
  __syncthreads();
  for (int r = 0; r < rows; r++) {
    float inv = 1.f / red[r][16];
    int gq = q0 + r;
    for (int m = t; m < N_; m += 256) {
      float val = Lg[r][m] * inv;
      atomicAdd(&hloc[__float_as_uint(val) >> 20], 1u);
      if (m == gq && gq > 0) diag[(size_t)bh * (N_ - 1) + gq - 1] = val;
    }
  }
  __syncthreads();
  for (int i = t; i < 4096; i += 256)
    if (hloc[i]) atomicAdd(&hist1[(size_t)bh * 4096 + i], hloc[i]);
}

// Refine passes: recompute logits (identical dot4), bin conditioned on prefix.
__global__ __launch_bounds__(256) void hist_ref2(
    const float* __restrict__ qb, const float* __restrict__ kb,
    const float* __restrict__ rowmax_g, const float* __restrict__ rowsum_g,
    const unsigned* __restrict__ pfx1, unsigned* __restrict__ hist2) {
  const int bh = blockIdx.x;
  const int q0 = blockIdx.y * 16;
  const int t = threadIdx.x;
  __shared__ float Qs[16][65];
  __shared__ float Ks[64][65];
  __shared__ unsigned hloc[4096];
  for (int i = t; i < 4096; i += 256) hloc[i] = 0u;
  {
    int r = t >> 4, d4 = (t & 15) * 4;
    int gq = q0 + r;
    float4 v = make_float4(0.f, 0.f, 0.f, 0.f);
    if (gq < N_) v = *(const float4*)&qb[((size_t)bh * N_ + gq) * HD_ + d4];
    Qs[r][d4 + 0] = v.x * 0.125f;
    Qs[r][d4 + 1] = v.y * 0.125f;
    Qs[r][d4 + 2] = v.z * 0.125f;
    Qs[r][d4 + 3] = v.w * 0.125f;
  }
  const int row = t >> 4, kc = (t & 15) * 4;
  const int gq = q0 + row;
  const bool rv = gq < N_;
  float M = 0.f, inv = 1.f;
  if (rv) { M = rowmax_g[(size_t)bh * N_ + gq]; inv = 1.f / rowsum_g[(size_t)bh * N_ + gq]; }
  const unsigned p = pfx1[bh];
  for (int n0 = 0; n0 < N_; n0 += 64) {
    __syncthreads();
    {
      int nn = t >> 2;
      int gn = n0 + nn;
      for (int i = 0; i < 4; i++) {
        int d = ((t & 3) + 4 * i) * 4;
        float4 v = make_float4(0.f, 0.f, 0.f, 0.f);
        if (gn < N_) v = *(const float4*)&kb[((size_t)bh * N_ + gn) * HD_ + d];
        Ks[nn][d + 0] = v.x; Ks[nn][d + 1] = v.y;
        Ks[nn][d + 2] = v.z; Ks[nn][d + 3] = v.w;
      }
    }
    __syncthreads();
    float l[4];
    dot4(&Qs[row][0], &Ks[kc][0], &Ks[kc + 1][0], &Ks[kc + 2][0], &Ks[kc + 3][0], l);
#pragma unroll
    for (int j = 0; j < 4; j++) {
      int gm = n0 + kc + j;
      if (rv && gm < N_) {
        float e = expf(l[j] - M);
        float v = e * inv;
        unsigned bits = __float_as_uint(v);
        if ((bits >> 20) == p) atomicAdd(&hloc[(bits >> 8) & 0xFFFu], 1u);
      }
    }
  }
  __syncthreads();
  for (int i = t; i < 4096; i += 256)
    if (hloc[i]) atomicAdd(&hist2[(size_t)bh * 4096 + i], hloc[i]);
}

__global__ __launch_bounds__(256) void hist_ref3(
    const float* __restrict__ qb, const float* __restrict__ kb,
    const float* __restrict__ rowmax_g, const float* __restrict__ rowsum_g,
    const unsigned* __restrict__ pfx2, unsigned* __restrict__ hist3) {
  const int bh = blockIdx.x;
  const int q0 = blockIdx.y * 16;
  const int t = threadIdx.x;
  __shared__ float Qs[16][65];
  __shared__ float Ks[64][65];
  __shared__ unsigned hloc[256];
  if (t < 256) hloc[t] = 0u;
  {
    int r = t >> 4, d4 = (t & 15) * 4;
    int gq = q0 + r;
    float4 v = make_float4(0.f, 0.f, 0.f, 0.f);
    if (gq < N_) v = *(const float4*)&qb[((size_t)bh * N_ + gq) * HD_ + d4];
    Qs[r][d4 + 0] = v.x * 0.125f;
    Qs[r][d4 + 1] = v.y * 0.125f;
    Qs[r][d4 + 2] = v.z * 0.125f;
    Qs[r][d4 + 3] = v.w * 0.125f;
  }
  const int row = t >> 4, kc = (t & 15) * 4;
  const int gq = q0 + row;
  const bool rv = gq < N_;
  float M = 0.f, inv = 1.f;
  if (rv) { M = rowmax_g[(size_t)bh * N_ + gq]; inv = 1.f / rowsum_g[(size_t)bh * N_ + gq]; }
  const unsigned p = pfx2[bh];
  for (int n0 = 0; n0 < N_; n0 += 64) {
    __syncthreads();
    {
      int nn = t >> 2;
      int gn = n0 + nn;
      for (int i = 0; i < 4; i++) {
        int d = ((t & 3) + 4 * i) * 4;
        float4 v = make_float4(0.f, 0.f, 0.f, 0.f);
        if (gn < N_) v = *(const float4*)&kb[((size_t)bh * N_ + gn) * HD_ + d];
        Ks[nn][d + 0] = v.x; Ks[nn][d + 1] = v.y;
        Ks[nn][d + 2] = v.z; Ks[nn][d + 3] = v.w;
      }
    }
    __syncthreads();
    float l[4];
    dot4(&Qs[row][0], &Ks[kc][0], &Ks[kc + 1][0], &Ks[kc + 2][0], &Ks[kc + 3][0], l);
#pragma unroll
    for (int j = 0; j < 4; j++) {
      int gm = n0 + kc + j;
      if (rv && gm < N_) {
        float e = expf(l[j] - M);
        float v = e * inv;
        unsigned bits = __float_as_uint(v);
        if ((bits >> 8) == p) atomicAdd(&hloc[bits & 0xFFu], 1u);
      }
    }
  }
  __syncthreads();
  if (t < 256 && hloc[t]) atomicAdd(&hist3[(size_t)bh * 256 + t], hloc[t]);
}

// AV with recomputed, sigma-masked P for 16 kept rows per block.
__global__ __launch_bounds__(256) void av_recompute(
    const float* __restrict__ qb, const float* __restrict__ kb,
    const float* __restrict__ vb, const int* __restrict__ kept,
    const float* __restrict__ rowmax_g, const float* __restrict__ rowsum_g,
    const unsigned* __restrict__ sigbits, float* __restrict__ out1) {
  const int bh = blockIdx.x;
  const int p0 = blockIdx.y * 16;
  const int b = bh / H_, h = bh % H_;
  const float sigma = __uint_as_float(sigbits[bh]);
  __shared__ float Qs[16][65];
  __shared__ float Ks[64][65];
  __shared__ float Vs[64][65];
  __shared__ float Ps[16][65];
  __shared__ int ridx[16];
  __shared__ float Ms[16], Ss[16];
  const int t = threadIdx.x;
  if (t < 16) {
    int p = p0 + t;
    int r = (p < KK_) ? kept[b * KK_ + p] : 0;
    ridx[t] = r;
    Ms[t] = rowmax_g[(size_t)bh * N_ + r];
    Ss[t] = rowsum_g[(size_t)bh * N_ + r];
  }
  __syncthreads();
  {
    int r = t >> 4, d4 = (t & 15) * 4;
    int gq = ridx[r];
    float4 v = *(const float4*)&qb[((size_t)bh * N_ + gq) * HD_ + d4];
    Qs[r][d4 + 0] = v.x * 0.125f;
    Qs[r][d4 + 1] = v.y * 0.125f;
    Qs[r][d4 + 2] = v.z * 0.125f;
    Qs[r][d4 + 3] = v.w * 0.125f;
  }
  const int row = t >> 4, kc = (t & 15) * 4;
  const bool pv = (p0 + row) < KK_;
  const float M = Ms[row];
  const float inv = 1.f / Ss[row];
  const int rowo = t >> 4, dc = (t & 15) * 4;
  float acc[4] = {};
  for (int n0 = 0; n0 < N_; n0 += 64) {
    __syncthreads();
    {
      int nn = t >> 2;
      int gn = n0 + nn;
      for (int i = 0; i < 4; i++) {
        int d = ((t & 3) + 4 * i) * 4;
        float4 kv = make_float4(0.f, 0.f, 0.f, 0.f);
        float4 vv = make_float4(0.f, 0.f, 0.f, 0.f);
        if (gn < N_) {
          kv = *(const float4*)&kb[((size_t)bh * N_ + gn) * HD_ + d];
          vv = *(const float4*)&vb[((size_t)bh * N_ + gn) * HD_ + d];
        }
        Ks[nn][d + 0] = kv.x; Ks[nn][d + 1] = kv.y;
        Ks[nn][d + 2] = kv.z; Ks[nn][d + 3] = kv.w;
        Vs[nn][d + 0] = vv.x; Vs[nn][d + 1] = vv.y;
        Vs[nn][d + 2] = vv.z; Vs[nn][d + 3] = vv.w;
      }
    }
    __syncthreads();
    float l[4];
    dot4(&Qs[row][0], &Ks[kc][0], &Ks[kc + 1][0], &Ks[kc + 2][0], &Ks[kc + 3][0], l);
#pragma unroll
    for (int j = 0; j < 4; j++) {
      int gm = n0 + kc + j;
      float val = 0.f;
      if (pv && gm < N_) {
        float e = expf(l[j] - M);
        float v = e * inv;
        val = (v >= sigma) ? v : 0.f;
      }
      Ps[row][kc + j] = val;
    }
    __syncthreads();
#pragma unroll 8
    for (int kk = 0; kk < 64; kk++) {
      float pvv = Ps[rowo][kk];
      acc[0] = __builtin_fmaf(pvv, Vs[kk][dc + 0], acc[0]);
      acc[1] = __builtin_fmaf(pvv, Vs[kk][dc + 1], acc[1]);
      acc[2] = __builtin_fmaf(pvv, Vs[kk][dc + 2], acc[2]);
      acc[3] = __builtin_fmaf(pvv, Vs[kk][dc + 3], acc[3]);
    }
  }
  int p = p0 + rowo;
  if (p < KK_) {
    float* dst = &out1[((size_t)(b * KK_ + p)) * C_ + h * HD_ + dc];
    dst[0] = acc[0]; dst[1] = acc[1]; dst[2] = acc[2]; dst[3] = acc[3];
  }
}

// ============================ shared kernels ============================
__global__ __launch_bounds__(64) void select_level(
    const unsigned* __restrict__ hist, int nbins,
    const unsigned* __restrict__ krem_in, const unsigned* __restrict__ pfx_in,
    unsigned* __restrict__ krem_out, unsigned* __restrict__ pfx_out, int shift) {
  const int bh = blockIdx.x;
  const int l = threadIdx.x;
  const int seg = nbins / 64;
  const unsigned krem = krem_in ? krem_in[bh] : KIDX_;
  const unsigned* hb = hist + (size_t)bh * nbins;
  __shared__ unsigned ps[64];
  unsigned psum = 0;
  int hi = nbins - 1 - l * seg;
  for (int i = 0; i < seg; i++) psum += hb[hi - i];
  ps[l] = psum;
  __syncthreads();
  if (l == 0) {
    unsigned cum = 0, before = 0;
    int bin = 0;
    for (int j = 0; j < 64; j++) {
      if (cum + ps[j] > krem) {
        unsigned c = cum;
        int hj = nbins - 1 - j * seg;
        for (int i = 0; i < seg; i++) {
          unsigned cnt = hb[hj - i];
          if (c + cnt > krem) { bin = hj - i; before = c; break; }
          c += cnt;
        }
        break;
      }
      cum += ps[j];
    }
    unsigned p = pfx_in ? pfx_in[bh] : 0u;
    pfx_out[bh] = (p << shift) | (unsigned)bin;
    krem_out[bh] = krem - before;
  }
}

__global__ __launch_bounds__(576) void rank_kernel(
    const float* __restrict__ diag, const unsigned* __restrict__ sigbits,
    int* __restrict__ kept) {
  const int b = blockIdx.x;
  const int i = threadIdx.x;
  __shared__ float sc[576];
  float s = 0.f;
  for (int h = 0; h < H_; h++) {
    float v = diag[(size_t)(b * H_ + h) * (N_ - 1) + i];
    float sg = __uint_as_float(sigbits[b * H_ + h]);
    if (v >= sg) s = fmaxf(s, v);
  }
  sc[i] = s;
  __syncthreads();
  int r = 0;
  for (int j = 0; j < 576; j++) {
    float sj = sc[j];
    if (sj > s || (sj == s && j < i)) r++;
  }
  if (r < KK_ - 1) kept[b * KK_ + r + 1] = i + 1;
  if (i == 0) kept[b * KK_] = 0;
}

__global__ __launch_bounds__(256) void gather_x(
    const float* __restrict__ xo, const int* __restrict__ kept,
    float* __restrict__ out2) {
  const int bp = blockIdx.x;
  const int b = bp / KK_, p = bp % KK_;
  const int src = kept[b * KK_ + p];
  const float* s = xo + ((size_t)b * N_ + src) * C_;
  float* d = out2 + (size_t)bp * C_;
  for (int c = threadIdx.x; c < C_; c += 256) d[c] = s[c];
}

__global__ __launch_bounds__(256) void proj_gemm(
    const float* __restrict__ Xi, const float* __restrict__ W,
    const float* __restrict__ bias, float* __restrict__ out) {
  __shared__ float Xs[16][65];
  __shared__ float Ws[16][65];
  const int m0 = blockIdx.x * 64;
  const int n0 = blockIdx.y * 64;
  const int t = threadIdx.x;
  const int tx = t & 15, ty = t >> 4;
  float acc[4][4] = {};
  for (int k0 = 0; k0 < 768; k0 += 16) {
    for (int i = 0; i < 4; i++) {
      int e = t + i * 256;
      int kk = e & 15, mm = e >> 4;
      Xs[kk][mm] = Xi[(size_t)(m0 + mm) * 768 + k0 + kk];
      Ws[kk][mm] = W[(size_t)(n0 + mm) * 768 + k0 + kk];
    }
    __syncthreads();
#pragma unroll
    for (int kk = 0; kk < 16; kk++) {
      float a[4], bb[4];
#pragma unroll
      for (int i = 0; i < 4; i++) a[i] = Xs[kk][tx + 16 * i];
#pragma unroll
      for (int j = 0; j < 4; j++) bb[j] = Ws[kk][ty + 16 * j];
#pragma unroll
      for (int i = 0; i < 4; i++)
#pragma unroll
        for (int j = 0; j < 4; j++) acc[i][j] += a[i] * bb[j];
    }
    __syncthreads();
  }
  for (int i = 0; i < 4; i++) {
    int gm = m0 + tx + 16 * i;  // M2 = 8320 = 130*64
    for (int j = 0; j < 4; j++) {
      int gn = n0 + ty + 16 * j;
      out[(size_t)gm * C_ + gn] = acc[i][j] + bias[gn];
    }
  }
}

// ---------------------------------------------------------------- launcher
extern "C" void kernel_launch(void* const* d_in, const int* in_sizes, int n_in,
                              void* d_out, int out_size, void* d_ws, size_t ws_size,
                              hipStream_t stream) {
  (void)in_sizes; (void)n_in; (void)out_size;
  const float* x    = (const float*)d_in[0];
  const float* xo   = (const float*)d_in[1];
  const float* qkvw = (const float*)d_in[2];
  const float* pw   = (const float*)d_in[3];
  const float* pb   = (const float*)d_in[4];

  char* ws = (char*)d_ws;
  size_t off = 0;
  auto alloc = [&](size_t bytes) -> char* {
    char* p = ws + off;
    off += (bytes + 255) & ~(size_t)255;
    return p;
  };
  const size_t szQ    = (size_t)BH_ * N_ * HD_ * 4;   // 28,366,848
  const size_t szAttn = (size_t)BH_ * NN2 * 4;        // 255,689,472
  const size_t szOut1 = (size_t)M2_ * C_ * 4;         // 25,559,040
  const size_t szDiag = (size_t)BH_ * (N_ - 1) * 4;
  const size_t szRow  = (size_t)BH_ * N_ * 4;
  const size_t szH12  = (size_t)BH_ * 4096 * 4;
  const size_t szH3   = (size_t)BH_ * 256 * 4;
  const size_t need_big = 3 * szQ + szAttn + szOut1 + szDiag +
                          2 * szH12 + szH3 + 8 * 768 + (size_t)B_ * KK_ * 4 + 65536;

  float* qb = (float*)alloc(szQ);
  float* kb = (float*)alloc(szQ);
  float* vb = (float*)alloc(szQ);
  float* out1 = (float*)alloc(szOut1);
  float* diag = (float*)alloc(szDiag);
  unsigned* hist1 = (unsigned*)alloc(szH12);
  unsigned* hist2 = (unsigned*)alloc(szH12);
  unsigned* hist3 = (unsigned*)alloc(szH3);
  unsigned* pfx1  = (unsigned*)alloc(BH_ * 4);
  unsigned* krem1 = (unsigned*)alloc(BH_ * 4);
  unsigned* pfx2  = (unsigned*)alloc(BH_ * 4);
  unsigned* krem2 = (unsigned*)alloc(BH_ * 4);
  unsigned* pfx3  = (unsigned*)alloc(BH_ * 4);
  unsigned* krem3 = (unsigned*)alloc(BH_ * 4);
  int* kept       = (int*)alloc((size_t)B_ * KK_ * 4);
  float* rowmax   = (float*)alloc(szRow);
  float* rowsum   = (float*)alloc(szRow);
  // big-path-only buffer, last:
  float* attn = (float*)alloc(szAttn);

  const bool big = (ws_size >= need_big);

  hipMemsetAsync(hist1, 0, szH12, stream);
  hipMemsetAsync(hist2, 0, szH12, stream);
  hipMemsetAsync(hist3, 0, szH3, stream);

  qkv_gemm<<<dim3(145, 36), 256, 0, stream>>>(x, qkvw, qb, kb, vb);

  float* outp = (float*)d_out;
  if (big) {
    attn_kernel<<<dim3(BH_, 37), 256, 0, stream>>>(qb, kb, attn, diag, hist1);
    select_level<<<BH_, 64, 0, stream>>>(hist1, 4096, nullptr, nullptr, krem1, pfx1, 12);
    hist_l2<<<dim3(BH_, 41), 256, 0, stream>>>(attn, pfx1, hist2);
    select_level<<<BH_, 64, 0, stream>>>(hist2, 4096, krem1, pfx1, krem2, pfx2, 12);
    hist_l3<<<dim3(BH_, 41), 256, 0, stream>>>(attn, pfx2, hist3);
    select_level<<<BH_, 64, 0, stream>>>(hist3, 256, krem2, pfx2, krem3, pfx3, 8);
    rank_kernel<<<B_, 576, 0, stream>>>(diag, pfx3, kept);
    gather_x<<<M2_, 256, 0, stream>>>(xo, kept, outp + (size_t)M2_ * C_);
    av_gemm<<<dim3(BH_, 17), 256, 0, stream>>>(attn, vb, kept, pfx3, out1);
  } else {
    attn_stats<<<dim3(BH_, 37), 256, 0, stream>>>(qb, kb, rowmax, rowsum, diag, hist1);
    select_level<<<BH_, 64, 0, stream>>>(hist1, 4096, nullptr, nullptr, krem1, pfx1, 12);
    hist_ref2<<<dim3(BH_, 37), 256, 0, stream>>>(qb, kb, rowmax, rowsum, pfx1, hist2);
    select_level<<<BH_, 64, 0, stream>>>(hist2, 4096, krem1, pfx1, krem2, pfx2, 12);
    hist_ref3<<<dim3(BH_, 37), 256, 0, stream>>>(qb, kb, rowmax, rowsum, pfx2, hist3);
    select_level<<<BH_, 64, 0, stream>>>(hist3, 256, krem2, pfx2, krem3, pfx3, 8);
    rank_kernel<<<B_, 576, 0, stream>>>(diag, pfx3, kept);
    gather_x<<<M2_, 256, 0, stream>>>(xo, kept, outp + (size_t)M2_ * C_);
    av_recompute<<<dim3(BH_, 33), 256, 0, stream>>>(qb, kb, vb, kept, rowmax, rowsum, pfx3, out1);
  }
  proj_gemm<<<dim3(130, 12), 256, 0, stream>>>(out1, pw, pb, outp);
}

// Round 3
// 1983.192 us; speedup vs baseline: 2.7309x; 2.7309x over previous
//
#include <hip/hip_runtime.h>
#include <cstdint>
#include <cstddef>

// Attention_41231686042092: ViT attention + softmax sparsification (per-(b,h)
// exact median threshold via 3-level radix select on f32 bit patterns) +
// diag-based token pruning + projection. All f32 (ranking needs exact-index
// fidelity vs the reference; bf16 noise would flip argsort order).
//
// Round-3 restructure: every QK-shaped pass uses one register-tiled
// microkernel (64x128 tile, 4x8 acc/thread, pad-69 LDS rows -> all LDS
// access patterns <=2-way bank aliasing). Logits are single ascending-d
// fmaf chains -> bit-identical across stats/hist/AV/rank passes.

namespace {
constexpr int B_  = 16;
constexpr int N_  = 577;
constexpr int C_  = 768;
constexpr int H_  = 12;
constexpr int HD_ = 64;
constexpr int BH_ = B_ * H_;            // 192
constexpr int KK_ = N_ - 57;            // 520 kept tokens
constexpr unsigned KIDX_ = 166464u;     // int(N*N*0.5), 0-based desc rank
constexpr int M1_ = B_ * N_;            // 9232
constexpr int M2_ = B_ * KK_;           // 8320
}

// ---------------------------------------------------------------- QKV GEMM
// Y = X @ W^T ; X:[M1,768], W:[2304,768]. 64x128 tile, 4x8 microtile.
__global__ __launch_bounds__(256) void qkv_gemm(
    const float* __restrict__ X, const float* __restrict__ W,
    float* __restrict__ qb, float* __restrict__ kb, float* __restrict__ vb) {
  __shared__ float Xs[64][37];
  __shared__ float Ws2[128][37];
  const int m0 = blockIdx.x * 64;
  const int n0 = blockIdx.y * 128;
  const int t = threadIdx.x;
  const int tx = t & 15, ty = t >> 4;
  const int sc = t & 7, sr = t >> 3;
  float acc[4][8] = {};
  for (int k0 = 0; k0 < 768; k0 += 32) {
    __syncthreads();
#pragma unroll
    for (int s = 0; s < 2; s++) {
      int r = sr + 32 * s;
      int gm = m0 + r;
      float4 v = make_float4(0.f, 0.f, 0.f, 0.f);
      if (gm < M1_) v = *(const float4*)&X[(size_t)gm * 768 + k0 + 4 * sc];
      Xs[r][4*sc+0] = v.x; Xs[r][4*sc+1] = v.y;
      Xs[r][4*sc+2] = v.z; Xs[r][4*sc+3] = v.w;
    }
#pragma unroll
    for (int s = 0; s < 4; s++) {
      int r = sr + 32 * s;
      float4 v = *(const float4*)&W[(size_t)(n0 + r) * 768 + k0 + 4 * sc];
      Ws2[r][4*sc+0] = v.x; Ws2[r][4*sc+1] = v.y;
      Ws2[r][4*sc+2] = v.z; Ws2[r][4*sc+3] = v.w;
    }
    __syncthreads();
#pragma unroll 8
    for (int kk = 0; kk < 32; kk++) {
      float a[4], bb[8];
#pragma unroll
      for (int i = 0; i < 4; i++) a[i] = Xs[tx + 16*i][kk];
#pragma unroll
      for (int j = 0; j < 8; j++) bb[j] = Ws2[8*ty + j][kk];
#pragma unroll
      for (int i = 0; i < 4; i++)
#pragma unroll
        for (int j = 0; j < 8; j++) acc[i][j] = __builtin_fmaf(a[i], bb[j], acc[i][j]);
    }
  }
  for (int i = 0; i < 4; i++) {
    int gm = m0 + tx + 16*i;
    if (gm >= M1_) continue;
    int b = gm / N_, n = gm % N_;
    for (int j = 0; j < 8; j++) {
      int gn = n0 + 8*ty + j;
      int which = gn / C_, rem = gn % C_;
      int h = rem >> 6, d = rem & 63;
      float* dst = (which == 0) ? qb : (which == 1) ? kb : vb;
      dst[(((size_t)(b * H_ + h)) * N_ + n) * HD_ + d] = acc[i][j];
    }
  }
}

// -------------------------------------------------- stats (QK pass #1)
// 64 q-rows/block, loops 5 col-tiles of 128. Online max/sum per row,
// logit-diagonal capture. rowmax is exact (order-free); rowsum is this
// kernel's value, stored and reused consistently by all later passes.
__global__ __launch_bounds__(256) void attn_stats(
    const float* __restrict__ qb, const float* __restrict__ kb,
    float* __restrict__ rowmax_g, float* __restrict__ rowsum_g,
    float* __restrict__ ldiag) {
  __shared__ float Qs[64][69];
  __shared__ float Ksf[128 * 69];
  const int bh = blockIdx.x;
  const int q0 = blockIdx.y * 64;
  const int t = threadIdx.x;
  const int tx = t & 15, ty = t >> 4;
  {
    const int c = t & 15, r0 = t >> 4;
#pragma unroll
    for (int s = 0; s < 4; s++) {
      int r = r0 + 16 * s;
      int gq = q0 + r;
      float4 v = make_float4(0.f, 0.f, 0.f, 0.f);
      if (gq < N_) v = *(const float4*)&qb[((size_t)bh * N_ + gq) * HD_ + 4 * c];
      Qs[r][4*c+0] = v.x * 0.125f; Qs[r][4*c+1] = v.y * 0.125f;
      Qs[r][4*c+2] = v.z * 0.125f; Qs[r][4*c+3] = v.w * 0.125f;
    }
  }
  float m[4], ss[4];
#pragma unroll
  for (int i = 0; i < 4; i++) { m[i] = -INFINITY; ss[i] = 0.f; }
  for (int n0 = 0; n0 < N_; n0 += 128) {
    __syncthreads();
    {
      const int c = t & 15, r0 = t >> 4;
#pragma unroll
      for (int s = 0; s < 8; s++) {
        int r = r0 + 16 * s;
        int gn = n0 + r;
        float4 v = make_float4(0.f, 0.f, 0.f, 0.f);
        if (gn < N_) v = *(const float4*)&kb[((size_t)bh * N_ + gn) * HD_ + 4 * c];
        float* kr = &Ksf[r * 69];
        kr[4*c+0] = v.x; kr[4*c+1] = v.y; kr[4*c+2] = v.z; kr[4*c+3] = v.w;
      }
    }
    __syncthreads();
    float l[4][8];
#pragma unroll
    for (int i = 0; i < 4; i++)
#pragma unroll
      for (int j = 0; j < 8; j++) l[i][j] = 0.f;
#pragma unroll 8
    for (int d = 0; d < 64; d++) {
      float a[4], bb[8];
#pragma unroll
      for (int i = 0; i < 4; i++) a[i] = Qs[tx + 16*i][d];
#pragma unroll
      for (int j = 0; j < 8; j++) bb[j] = Ksf[(8*ty + j) * 69 + d];
#pragma unroll
      for (int i = 0; i < 4; i++)
#pragma unroll
        for (int j = 0; j < 8; j++) l[i][j] = __builtin_fmaf(a[i], bb[j], l[i][j]);
    }
    int cbase = n0 + 8 * ty;
    int cv = N_ - cbase; if (cv > 8) cv = 8;
    if (cv > 0) {
#pragma unroll
      for (int i = 0; i < 4; i++) {
        int gq = q0 + tx + 16*i;
        if (gq >= N_) continue;
        float tmax = -INFINITY;
        for (int j = 0; j < 8; j++) if (j < cv) tmax = fmaxf(tmax, l[i][j]);
        float mn = fmaxf(m[i], tmax);
        ss[i] *= expf(m[i] - mn);
        for (int j = 0; j < 8; j++) if (j < cv) ss[i] += expf(l[i][j] - mn);
        m[i] = mn;
        int dj = gq - cbase;
        if (dj >= 0 && dj < cv) ldiag[(size_t)bh * N_ + gq] = l[i][dj];
      }
    }
  }
  __syncthreads();
  float* Mred = Ksf;            // overlay (Ks dead now): 64x16
  float* Sred = Ksf + 1024;
#pragma unroll
  for (int i = 0; i < 4; i++) {
    int row = tx + 16*i;
    Mred[row * 16 + ty] = m[i];
    Sred[row * 16 + ty] = ss[i];
  }
  __syncthreads();
  if (t < 64) {
    int gq = q0 + t;
    if (gq < N_) {
      float M = -INFINITY;
      for (int k = 0; k < 16; k++) M = fmaxf(M, Mred[t*16 + k]);
      float S = 0.f;
      for (int k = 0; k < 16; k++) S += expf(Mred[t*16+k] - M) * Sred[t*16+k];
      rowmax_g[(size_t)bh * N_ + gq] = M;
      rowsum_g[(size_t)bh * N_ + gq] = S;
    }
  }
}

// ----------------------------------------- histogram passes (QK #2,#3,#4)
// MODE 0: top-12-bit hist (ballot-coalesced atomics: softmax values cluster
//         into few bins -> 1 atomic per wave in the common case).
// MODE 1: bits[19:8] conditioned on pfx1.  MODE 2: bits[7:0] on pfx2.
template <int MODE>
__global__ __launch_bounds__(256) void hist_pass(
    const float* __restrict__ qb, const float* __restrict__ kb,
    const float* __restrict__ rowmax_g, const float* __restrict__ rowsum_g,
    const unsigned* __restrict__ pfx_in, unsigned* __restrict__ hist_out) {
  constexpr int HB = (MODE == 2) ? 256 : 4096;
  __shared__ float Qs[64][69];
  __shared__ float Ksf[128 * 69];
  __shared__ unsigned hloc[HB];
  const int bh = blockIdx.x;
  const int q0 = blockIdx.y * 64;
  const int t = threadIdx.x;
  const int tx = t & 15, ty = t >> 4;
  for (int i = t; i < HB; i += 256) hloc[i] = 0u;
  const unsigned pf = (MODE == 0) ? 0u : pfx_in[bh];
  {
    const int c = t & 15, r0 = t >> 4;
#pragma unroll
    for (int s = 0; s < 4; s++) {
      int r = r0 + 16 * s;
      int gq = q0 + r;
      float4 v = make_float4(0.f, 0.f, 0.f, 0.f);
      if (gq < N_) v = *(const float4*)&qb[((size_t)bh * N_ + gq) * HD_ + 4 * c];
      Qs[r][4*c+0] = v.x * 0.125f; Qs[r][4*c+1] = v.y * 0.125f;
      Qs[r][4*c+2] = v.z * 0.125f; Qs[r][4*c+3] = v.w * 0.125f;
    }
  }
  float M[4], inv[4];
#pragma unroll
  for (int i = 0; i < 4; i++) {
    int gq = q0 + tx + 16*i;
    if (gq < N_) {
      M[i] = rowmax_g[(size_t)bh * N_ + gq];
      inv[i] = 1.f / rowsum_g[(size_t)bh * N_ + gq];
    } else { M[i] = 0.f; inv[i] = 0.f; }
  }
  for (int n0 = 0; n0 < N_; n0 += 128) {
    __syncthreads();
    {
      const int c = t & 15, r0 = t >> 4;
#pragma unroll
      for (int s = 0; s < 8; s++) {
        int r = r0 + 16 * s;
        int gn = n0 + r;
        float4 v = make_float4(0.f, 0.f, 0.f, 0.f);
        if (gn < N_) v = *(const float4*)&kb[((size_t)bh * N_ + gn) * HD_ + 4 * c];
        float* kr = &Ksf[r * 69];
        kr[4*c+0] = v.x; kr[4*c+1] = v.y; kr[4*c+2] = v.z; kr[4*c+3] = v.w;
      }
    }
    __syncthreads();
    float l[4][8];
#pragma unroll
    for (int i = 0; i < 4; i++)
#pragma unroll
      for (int j = 0; j < 8; j++) l[i][j] = 0.f;
#pragma unroll 8
    for (int d = 0; d < 64; d++) {
      float a[4], bb[8];
#pragma unroll
      for (int i = 0; i < 4; i++) a[i] = Qs[tx + 16*i][d];
#pragma unroll
      for (int j = 0; j < 8; j++) bb[j] = Ksf[(8*ty + j) * 69 + d];
#pragma unroll
      for (int i = 0; i < 4; i++)
#pragma unroll
        for (int j = 0; j < 8; j++) l[i][j] = __builtin_fmaf(a[i], bb[j], l[i][j]);
    }
    int cbase = n0 + 8 * ty;
#pragma unroll
    for (int i = 0; i < 4; i++) {
      int gq = q0 + tx + 16 * i;
#pragma unroll
      for (int j = 0; j < 8; j++) {
        bool valid = (gq < N_) && (cbase + j < N_);
        if (MODE == 0) {
          unsigned bin = 0xFFFFu;
          if (valid) {
            float e = expf(l[i][j] - M[i]);
            float v = e * inv[i];
            bin = __float_as_uint(v) >> 20;
          }
          unsigned lead = (unsigned)__builtin_amdgcn_readfirstlane((int)bin);
          unsigned long long mm = __ballot(bin == lead);
          if (bin == lead) {
            if (lead != 0xFFFFu && (t & 63) == (__ffsll((unsigned long long)mm) - 1))
              atomicAdd(&hloc[lead], (unsigned)__popcll(mm));
          } else if (bin != 0xFFFFu) {
            atomicAdd(&hloc[bin], 1u);
          }
        } else if (valid) {
          float e = expf(l[i][j] - M[i]);
          float v = e * inv[i];
          unsigned bits = __float_as_uint(v);
          if (MODE == 1) {
            if ((bits >> 20) == pf) atomicAdd(&hloc[(bits >> 8) & 0xFFFu], 1u);
          } else {
            if ((bits >> 8) == pf) atomicAdd(&hloc[bits & 0xFFu], 1u);
          }
        }
      }
    }
  }
  __syncthreads();
  for (int i = t; i < HB; i += 256)
    if (hloc[i]) atomicAdd(&hist_out[(size_t)bh * HB + i], hloc[i]);
}

// ------------------------------------------------------ radix-select levels
__global__ __launch_bounds__(64) void select_level(
    const unsigned* __restrict__ hist, int nbins,
    const unsigned* __restrict__ krem_in, const unsigned* __restrict__ pfx_in,
    unsigned* __restrict__ krem_out, unsigned* __restrict__ pfx_out, int shift) {
  const int bh = blockIdx.x;
  const int l = threadIdx.x;
  const int seg = nbins / 64;
  const unsigned krem = krem_in ? krem_in[bh] : KIDX_;
  const unsigned* hb = hist + (size_t)bh * nbins;
  __shared__ unsigned ps[64];
  unsigned psum = 0;
  int hi = nbins - 1 - l * seg;
  for (int i = 0; i < seg; i++) psum += hb[hi - i];
  ps[l] = psum;
  __syncthreads();
  if (l == 0) {
    unsigned cum = 0, before = 0;
    int bin = 0;
    for (int j = 0; j < 64; j++) {
      if (cum + ps[j] > krem) {
        unsigned c = cum;
        int hj = nbins - 1 - j * seg;
        for (int i = 0; i < seg; i++) {
          unsigned cnt = hb[hj - i];
          if (c + cnt > krem) { bin = hj - i; before = c; break; }
          c += cnt;
        }
        break;
      }
      cum += ps[j];
    }
    unsigned p = pfx_in ? pfx_in[bh] : 0u;
    pfx_out[bh] = (p << shift) | (unsigned)bin;
    krem_out[bh] = krem - before;
  }
}

// ------------------------------------------------- token ranking (stable)
__global__ __launch_bounds__(576) void rank_kernel(
    const float* __restrict__ ldiag, const float* __restrict__ rowmax_g,
    const float* __restrict__ rowsum_g, const unsigned* __restrict__ sigbits,
    int* __restrict__ kept) {
  const int b = blockIdx.x;
  const int i = threadIdx.x;  // token i+1
  __shared__ float sc[576];
  float s = 0.f;
  for (int h = 0; h < H_; h++) {
    int bh = b * H_ + h;
    float l = ldiag[(size_t)bh * N_ + (i + 1)];
    float M = rowmax_g[(size_t)bh * N_ + (i + 1)];
    float inv = 1.f / rowsum_g[(size_t)bh * N_ + (i + 1)];
    float e = expf(l - M);
    float v = e * inv;   // bit-identical to hist/AV computation
    float sg = __uint_as_float(sigbits[bh]);
    if (v >= sg) s = fmaxf(s, v);
  }
  sc[i] = s;
  __syncthreads();
  int r = 0;
  for (int j = 0; j < 576; j++) {
    float sj = sc[j];
    if (sj > s || (sj == s && j < i)) r++;
  }
  if (r < KK_ - 1) kept[b * KK_ + r + 1] = i + 1;
  if (i == 0) kept[b * KK_] = 0;
}

// ------------------------------------------------------ gather x_original
__global__ __launch_bounds__(256) void gather_x(
    const float* __restrict__ xo, const int* __restrict__ kept,
    float* __restrict__ out2) {
  const int bp = blockIdx.x;
  const int b = bp / KK_, p = bp % KK_;
  const int src = kept[b * KK_ + p];
  const float* s = xo + ((size_t)b * N_ + src) * C_;
  float* d = out2 + (size_t)bp * C_;
  for (int c = threadIdx.x; c < C_; c += 256) d[c] = s[c];
}

// ------------------------------------------- AV (QK recompute #5 + PV)
// 64 kept rows/block; per 64-col tile: QK (4x4) -> mask -> P overlays K
// in LDS -> PV (4x4). 53.8KB LDS -> 3 blocks/CU.
__global__ __launch_bounds__(256) void av_kernel(
    const float* __restrict__ qb, const float* __restrict__ kb,
    const float* __restrict__ vb, const int* __restrict__ kept,
    const float* __restrict__ rowmax_g, const float* __restrict__ rowsum_g,
    const unsigned* __restrict__ sigbits, float* __restrict__ out1) {
  __shared__ float Qs[64][69];
  __shared__ float Ksf[64 * 69];   // overlaid by P after QK
  __shared__ float Vs[64][69];
  __shared__ int ridx[64];
  __shared__ float Ml[64], Il[64];
  const int bh = blockIdx.x;
  const int p0 = blockIdx.y * 64;
  const int b = bh / H_, h = bh % H_;
  const float sigma = __uint_as_float(sigbits[bh]);
  const int t = threadIdx.x;
  const int tx = t & 15, ty = t >> 4;
  if (t < 64) {
    int pp = p0 + t;
    int r = (pp < KK_) ? kept[b * KK_ + pp] : 0;
    ridx[t] = r;
    Ml[t] = rowmax_g[(size_t)bh * N_ + r];
    Il[t] = 1.f / rowsum_g[(size_t)bh * N_ + r];
  }
  __syncthreads();
  {
    const int c = t & 15, r0 = t >> 4;
#pragma unroll
    for (int s = 0; s < 4; s++) {
      int r = r0 + 16 * s;
      int gq = ridx[r];
      float4 v = *(const float4*)&qb[((size_t)bh * N_ + gq) * HD_ + 4 * c];
      Qs[r][4*c+0] = v.x * 0.125f; Qs[r][4*c+1] = v.y * 0.125f;
      Qs[r][4*c+2] = v.z * 0.125f; Qs[r][4*c+3] = v.w * 0.125f;
    }
  }
  float M[4], inv[4];
#pragma unroll
  for (int i = 0; i < 4; i++) { int row = tx + 16*i; M[i] = Ml[row]; inv[i] = Il[row]; }
  float acc[4][4] = {};
  for (int n0 = 0; n0 < N_; n0 += 64) {
    __syncthreads();
    {
      const int c = t & 15, r0 = t >> 4;
#pragma unroll
      for (int s = 0; s < 4; s++) {
        int r = r0 + 16 * s;
        int gn = n0 + r;
        float4 kv = make_float4(0.f, 0.f, 0.f, 0.f);
        float4 vv = make_float4(0.f, 0.f, 0.f, 0.f);
        if (gn < N_) {
          kv = *(const float4*)&kb[((size_t)bh * N_ + gn) * HD_ + 4 * c];
          vv = *(const float4*)&vb[((size_t)bh * N_ + gn) * HD_ + 4 * c];
        }
        float* kr = &Ksf[r * 69];
        kr[4*c+0] = kv.x; kr[4*c+1] = kv.y; kr[4*c+2] = kv.z; kr[4*c+3] = kv.w;
        Vs[r][4*c+0] = vv.x; Vs[r][4*c+1] = vv.y;
        Vs[r][4*c+2] = vv.z; Vs[r][4*c+3] = vv.w;
      }
    }
    __syncthreads();
    float l[4][4];
#pragma unroll
    for (int i = 0; i < 4; i++)
#pragma unroll
      for (int j = 0; j < 4; j++) l[i][j] = 0.f;
#pragma unroll 8
    for (int d = 0; d < 64; d++) {
      float a[4], bb[4];
#pragma unroll
      for (int i = 0; i < 4; i++) a[i] = Qs[tx + 16*i][d];
#pragma unroll
      for (int j = 0; j < 4; j++) bb[j] = Ksf[(4*ty + j) * 69 + d];
#pragma unroll
      for (int i = 0; i < 4; i++)
#pragma unroll
        for (int j = 0; j < 4; j++) l[i][j] = __builtin_fmaf(a[i], bb[j], l[i][j]);
    }
    __syncthreads();   // QK done -> overlay P on Ks
#pragma unroll
    for (int i = 0; i < 4; i++) {
#pragma unroll
      for (int j = 0; j < 4; j++) {
        float e = expf(l[i][j] - M[i]);
        float v = e * inv[i];
        float pm = (v >= sigma) ? v : 0.f;   // padded cols harmless: V=0
        Ksf[(tx + 16*i) * 69 + 4*ty + j] = pm;
      }
    }
    __syncthreads();
#pragma unroll 8
    for (int n = 0; n < 64; n++) {
      float pa[4], vv[4];
#pragma unroll
      for (int i = 0; i < 4; i++) pa[i] = Ksf[(tx + 16*i) * 69 + n];
#pragma unroll
      for (int j = 0; j < 4; j++) vv[j] = Vs[n][4*ty + j];
#pragma unroll
      for (int i = 0; i < 4; i++)
#pragma unroll
        for (int j = 0; j < 4; j++) acc[i][j] = __builtin_fmaf(pa[i], vv[j], acc[i][j]);
    }
  }
#pragma unroll
  for (int i = 0; i < 4; i++) {
    int pp = p0 + tx + 16*i;
    if (pp >= KK_) continue;
#pragma unroll
    for (int j = 0; j < 4; j++) {
      out1[((size_t)(b * KK_ + pp)) * C_ + h * HD_ + 4*ty + j] = acc[i][j];
    }
  }
}

// ------------------------------------------------------------ proj GEMM
__global__ __launch_bounds__(256) void proj_gemm(
    const float* __restrict__ Xi, const float* __restrict__ W,
    const float* __restrict__ bias, float* __restrict__ out) {
  __shared__ float Xs[64][37];
  __shared__ float Ws2[128][37];
  const int m0 = blockIdx.x * 64;
  const int n0 = blockIdx.y * 128;
  const int t = threadIdx.x;
  const int tx = t & 15, ty = t >> 4;
  const int sc = t & 7, sr = t >> 3;
  float acc[4][8] = {};
  for (int k0 = 0; k0 < 768; k0 += 32) {
    __syncthreads();
#pragma unroll
    for (int s = 0; s < 2; s++) {
      int r = sr + 32 * s;
      float4 v = *(const float4*)&Xi[(size_t)(m0 + r) * 768 + k0 + 4 * sc];
      Xs[r][4*sc+0] = v.x; Xs[r][4*sc+1] = v.y;
      Xs[r][4*sc+2] = v.z; Xs[r][4*sc+3] = v.w;
    }
#pragma unroll
    for (int s = 0; s < 4; s++) {
      int r = sr + 32 * s;
      float4 v = *(const float4*)&W[(size_t)(n0 + r) * 768 + k0 + 4 * sc];
      Ws2[r][4*sc+0] = v.x; Ws2[r][4*sc+1] = v.y;
      Ws2[r][4*sc+2] = v.z; Ws2[r][4*sc+3] = v.w;
    }
    __syncthreads();
#pragma unroll 8
    for (int kk = 0; kk < 32; kk++) {
      float a[4], bb[8];
#pragma unroll
      for (int i = 0; i < 4; i++) a[i] = Xs[tx + 16*i][kk];
#pragma unroll
      for (int j = 0; j < 8; j++) bb[j] = Ws2[8*ty + j][kk];
#pragma unroll
      for (int i = 0; i < 4; i++)
#pragma unroll
        for (int j = 0; j < 8; j++) acc[i][j] = __builtin_fmaf(a[i], bb[j], acc[i][j]);
    }
  }
  for (int i = 0; i < 4; i++) {
    int gm = m0 + tx + 16*i;   // M2 = 8320 = 130*64, no guard
    for (int j = 0; j < 8; j++) {
      int gn = n0 + 8*ty + j;
      out[(size_t)gm * C_ + gn] = acc[i][j] + bias[gn];
    }
  }
}

// ---------------------------------------------------------------- launcher
extern "C" void kernel_launch(void* const* d_in, const int* in_sizes, int n_in,
                              void* d_out, int out_size, void* d_ws, size_t ws_size,
                              hipStream_t stream) {
  (void)in_sizes; (void)n_in; (void)out_size; (void)ws_size;
  const float* x    = (const float*)d_in[0];
  const float* xo   = (const float*)d_in[1];
  const float* qkvw = (const float*)d_in[2];
  const float* pw   = (const float*)d_in[3];
  const float* pb   = (const float*)d_in[4];

  char* ws = (char*)d_ws;
  size_t off = 0;
  auto alloc = [&](size_t bytes) -> char* {
    char* p = ws + off;
    off += (bytes + 255) & ~(size_t)255;
    return p;
  };
  const size_t szQ    = (size_t)BH_ * N_ * HD_ * 4;   // 28.4 MB
  const size_t szOut1 = (size_t)M2_ * C_ * 4;         // 25.6 MB
  const size_t szRow  = (size_t)BH_ * N_ * 4;         // 443 KB
  const size_t szH12  = (size_t)BH_ * 4096 * 4;       // 3.1 MB
  const size_t szH3   = (size_t)BH_ * 256 * 4;

  float* qb     = (float*)alloc(szQ);
  float* kb     = (float*)alloc(szQ);
  float* vb     = (float*)alloc(szQ);
  float* out1   = (float*)alloc(szOut1);
  float* ldiag  = (float*)alloc(szRow);
  float* rowmax = (float*)alloc(szRow);
  float* rowsum = (float*)alloc(szRow);
  unsigned* hist1 = (unsigned*)alloc(szH12);
  unsigned* hist2 = (unsigned*)alloc(szH12);
  unsigned* hist3 = (unsigned*)alloc(szH3);
  unsigned* pfx1  = (unsigned*)alloc(BH_ * 4);
  unsigned* krem1 = (unsigned*)alloc(BH_ * 4);
  unsigned* pfx2  = (unsigned*)alloc(BH_ * 4);
  unsigned* krem2 = (unsigned*)alloc(BH_ * 4);
  unsigned* pfx3  = (unsigned*)alloc(BH_ * 4);
  unsigned* krem3 = (unsigned*)alloc(BH_ * 4);
  int* kept       = (int*)alloc((size_t)B_ * KK_ * 4);

  hipMemsetAsync(hist1, 0, szH12, stream);
  hipMemsetAsync(hist2, 0, szH12, stream);
  hipMemsetAsync(hist3, 0, szH3, stream);

  qkv_gemm<<<dim3(145, 18), 256, 0, stream>>>(x, qkvw, qb, kb, vb);
  attn_stats<<<dim3(BH_, 10), 256, 0, stream>>>(qb, kb, rowmax, rowsum, ldiag);
  hist_pass<0><<<dim3(BH_, 10), 256, 0, stream>>>(qb, kb, rowmax, rowsum, nullptr, hist1);
  select_level<<<BH_, 64, 0, stream>>>(hist1, 4096, nullptr, nullptr, krem1, pfx1, 12);
  hist_pass<1><<<dim3(BH_, 10), 256, 0, stream>>>(qb, kb, rowmax, rowsum, pfx1, hist2);
  select_level<<<BH_, 64, 0, stream>>>(hist2, 4096, krem1, pfx1, krem2, pfx2, 12);
  hist_pass<2><<<dim3(BH_, 10), 256, 0, stream>>>(qb, kb, rowmax, rowsum, pfx2, hist3);
  select_level<<<BH_, 64, 0, stream>>>(hist3, 256, krem2, pfx2, krem3, pfx3, 8);
  rank_kernel<<<B_, 576, 0, stream>>>(ldiag, rowmax, rowsum, pfx3, kept);

  float* outp = (float*)d_out;
  gather_x<<<M2_, 256, 0, stream>>>(xo, kept, outp + (size_t)M2_ * C_);
  av_kernel<<<dim3(BH_, 9), 256, 0, stream>>>(qb, kb, vb, kept, rowmax, rowsum, pfx3, out1);
  proj_gemm<<<dim3(130, 6), 256, 0, stream>>>(out1, pw, pb, outp);
}

// Round 4
// 1800.916 us; speedup vs baseline: 3.0073x; 1.1012x over previous
//
#include <hip/hip_runtime.h>
#include <cstdint>
#include <cstddef>

// Attention_41231686042092: ViT attention + softmax sparsification (per-(b,h)
// exact median threshold via 3-level radix select on f32 bit patterns) +
// diag-based token pruning + projection. All f32 (ranking needs exact-index
// fidelity vs the reference; bf16 noise would flip argsort order).
//
// Round-4: all microkernels vectorized to ds_read_b128 (float4 k-blocks) with
// [rows][68]-float LDS tiles (272B rows: 16B-aligned, <=2-way bank aliasing).
// Every logit remains a single ascending-k fmaf chain (fma4) -> bit-identical
// across stats/hist/AV/rank passes.

namespace {
constexpr int B_  = 16;
constexpr int N_  = 577;
constexpr int C_  = 768;
constexpr int H_  = 12;
constexpr int HD_ = 64;
constexpr int BH_ = B_ * H_;            // 192
constexpr int KK_ = N_ - 57;            // 520 kept tokens
constexpr unsigned KIDX_ = 166464u;     // int(N*N*0.5), 0-based desc rank
constexpr int M1_ = B_ * N_;            // 9232
constexpr int M2_ = B_ * KK_;           // 8320
}

// Ascending-k fused chain: acc = fma(a.w, b.w, fma(a.z, b.z, ...)) in x,y,z,w
// order. Used by ALL dot products => deterministic, pass-consistent bits.
__device__ __forceinline__ void fma4(const float4& a, const float4& b, float& acc) {
  acc = __builtin_fmaf(a.x, b.x, acc);
  acc = __builtin_fmaf(a.y, b.y, acc);
  acc = __builtin_fmaf(a.z, b.z, acc);
  acc = __builtin_fmaf(a.w, b.w, acc);
}

// ---------------------------------------------------------------- QKV GEMM
// Y = X @ W^T ; X:[M1,768], W:[2304,768]. 64x128 tile, 4x8 microtile,
// k-chunk 64. a rows tx+16i, b rows ty+16j.
__global__ __launch_bounds__(256) void qkv_gemm(
    const float* __restrict__ X, const float* __restrict__ W,
    float* __restrict__ qb, float* __restrict__ kb, float* __restrict__ vb) {
  __shared__ __align__(16) float Xs[64][68];
  __shared__ __align__(16) float Ws2[128][68];
  const int m0 = blockIdx.x * 64;
  const int n0 = blockIdx.y * 128;
  const int t = threadIdx.x;
  const int tx = t & 15, ty = t >> 4;
  float acc[4][8] = {};
  for (int k0 = 0; k0 < 768; k0 += 64) {
    __syncthreads();
    {
      const int c = t & 15, r0 = t >> 4;
#pragma unroll
      for (int s = 0; s < 4; s++) {
        int r = r0 + 16 * s;
        int gm = m0 + r;
        float4 v = make_float4(0.f, 0.f, 0.f, 0.f);
        if (gm < M1_) v = *(const float4*)&X[(size_t)gm * 768 + k0 + 4 * c];
        *(float4*)&Xs[r][4 * c] = v;
      }
#pragma unroll
      for (int s = 0; s < 8; s++) {
        int r = r0 + 16 * s;
        float4 v = *(const float4*)&W[(size_t)(n0 + r) * 768 + k0 + 4 * c];
        *(float4*)&Ws2[r][4 * c] = v;
      }
    }
    __syncthreads();
#pragma unroll 2
    for (int d4 = 0; d4 < 16; d4++) {
      float4 a4[4], b4[8];
#pragma unroll
      for (int i = 0; i < 4; i++) a4[i] = *(const float4*)&Xs[tx + 16 * i][4 * d4];
#pragma unroll
      for (int j = 0; j < 8; j++) b4[j] = *(const float4*)&Ws2[ty + 16 * j][4 * d4];
#pragma unroll
      for (int i = 0; i < 4; i++)
#pragma unroll
        for (int j = 0; j < 8; j++) fma4(a4[i], b4[j], acc[i][j]);
    }
  }
  for (int i = 0; i < 4; i++) {
    int gm = m0 + tx + 16 * i;
    if (gm >= M1_) continue;
    int b = gm / N_, n = gm % N_;
    for (int j = 0; j < 8; j++) {
      int gn = n0 + ty + 16 * j;
      int which = gn / C_, rem = gn % C_;
      int h = rem >> 6, d = rem & 63;
      float* dst = (which == 0) ? qb : (which == 1) ? kb : vb;
      dst[(((size_t)(b * H_ + h)) * N_ + n) * HD_ + d] = acc[i][j];
    }
  }
}

// -------------------------------------------------- stats (QK pass #1)
// 64 q-rows/block x 5 col-tiles of 128. Online max/sum per row, logit-diag
// capture. rowmax exact (order-free); rowsum stored & reused by all passes.
__global__ __launch_bounds__(256) void attn_stats(
    const float* __restrict__ qb, const float* __restrict__ kb,
    float* __restrict__ rowmax_g, float* __restrict__ rowsum_g,
    float* __restrict__ ldiag) {
  __shared__ __align__(16) float Qs[64][68];
  __shared__ __align__(16) float Ksf[128][68];
  const int bh = blockIdx.x;
  const int q0 = blockIdx.y * 64;
  const int t = threadIdx.x;
  const int tx = t & 15, ty = t >> 4;
  {
    const int c = t & 15, r0 = t >> 4;
#pragma unroll
    for (int s = 0; s < 4; s++) {
      int r = r0 + 16 * s;
      int gq = q0 + r;
      float4 v = make_float4(0.f, 0.f, 0.f, 0.f);
      if (gq < N_) v = *(const float4*)&qb[((size_t)bh * N_ + gq) * HD_ + 4 * c];
      v.x *= 0.125f; v.y *= 0.125f; v.z *= 0.125f; v.w *= 0.125f;
      *(float4*)&Qs[r][4 * c] = v;
    }
  }
  float m[4], ss[4];
#pragma unroll
  for (int i = 0; i < 4; i++) { m[i] = -INFINITY; ss[i] = 0.f; }
  for (int n0 = 0; n0 < N_; n0 += 128) {
    __syncthreads();
    {
      const int c = t & 15, r0 = t >> 4;
#pragma unroll
      for (int s = 0; s < 8; s++) {
        int r = r0 + 16 * s;
        int gn = n0 + r;
        float4 v = make_float4(0.f, 0.f, 0.f, 0.f);
        if (gn < N_) v = *(const float4*)&kb[((size_t)bh * N_ + gn) * HD_ + 4 * c];
        *(float4*)&Ksf[r][4 * c] = v;
      }
    }
    __syncthreads();
    float l[4][8];
#pragma unroll
    for (int i = 0; i < 4; i++)
#pragma unroll
      for (int j = 0; j < 8; j++) l[i][j] = 0.f;
#pragma unroll 2
    for (int d4 = 0; d4 < 16; d4++) {
      float4 a4[4], b4[8];
#pragma unroll
      for (int i = 0; i < 4; i++) a4[i] = *(const float4*)&Qs[tx + 16 * i][4 * d4];
#pragma unroll
      for (int j = 0; j < 8; j++) b4[j] = *(const float4*)&Ksf[ty + 16 * j][4 * d4];
#pragma unroll
      for (int i = 0; i < 4; i++)
#pragma unroll
        for (int j = 0; j < 8; j++) fma4(a4[i], b4[j], l[i][j]);
    }
#pragma unroll
    for (int i = 0; i < 4; i++) {
      int gq = q0 + tx + 16 * i;
      float tmax = -INFINITY;
#pragma unroll
      for (int j = 0; j < 8; j++)
        if (n0 + ty + 16 * j < N_) tmax = fmaxf(tmax, l[i][j]);
      float mn = fmaxf(m[i], tmax);
      ss[i] *= expf(m[i] - mn);
#pragma unroll
      for (int j = 0; j < 8; j++) {
        int col = n0 + ty + 16 * j;
        if (col < N_) {
          ss[i] += expf(l[i][j] - mn);
          if (col == gq) ldiag[(size_t)bh * N_ + gq] = l[i][j];
        }
      }
      m[i] = mn;
    }
  }
  __syncthreads();
  float* Mred = &Ksf[0][0];   // overlay (Ksf dead): 64x16 each
  float* Sred = &Ksf[0][0] + 1024;
#pragma unroll
  for (int i = 0; i < 4; i++) {
    int row = tx + 16 * i;
    Mred[row * 16 + ty] = m[i];
    Sred[row * 16 + ty] = ss[i];
  }
  __syncthreads();
  if (t < 64) {
    int gq = q0 + t;
    if (gq < N_) {
      float M = -INFINITY;
      for (int k = 0; k < 16; k++) M = fmaxf(M, Mred[t * 16 + k]);
      float S = 0.f;
      for (int k = 0; k < 16; k++) S += expf(Mred[t * 16 + k] - M) * Sred[t * 16 + k];
      rowmax_g[(size_t)bh * N_ + gq] = M;
      rowsum_g[(size_t)bh * N_ + gq] = S;
    }
  }
}

// ----------------------------------------- histogram passes (QK #2,#3,#4)
// MODE 0: top-12-bit hist (ballot-coalesced LDS atomics).
// MODE 1: bits[19:8] on pfx1.  MODE 2: bits[7:0] on pfx2.
template <int MODE>
__global__ __launch_bounds__(256) void hist_pass(
    const float* __restrict__ qb, const float* __restrict__ kb,
    const float* __restrict__ rowmax_g, const float* __restrict__ rowsum_g,
    const unsigned* __restrict__ pfx_in, unsigned* __restrict__ hist_out) {
  constexpr int HB = (MODE == 2) ? 256 : 4096;
  __shared__ __align__(16) float Qs[64][68];
  __shared__ __align__(16) float Ksf[128][68];
  __shared__ unsigned hloc[HB];
  const int bh = blockIdx.x;
  const int q0 = blockIdx.y * 64;
  const int t = threadIdx.x;
  const int tx = t & 15, ty = t >> 4;
  for (int i = t; i < HB; i += 256) hloc[i] = 0u;
  const unsigned pf = (MODE == 0) ? 0u : pfx_in[bh];
  {
    const int c = t & 15, r0 = t >> 4;
#pragma unroll
    for (int s = 0; s < 4; s++) {
      int r = r0 + 16 * s;
      int gq = q0 + r;
      float4 v = make_float4(0.f, 0.f, 0.f, 0.f);
      if (gq < N_) v = *(const float4*)&qb[((size_t)bh * N_ + gq) * HD_ + 4 * c];
      v.x *= 0.125f; v.y *= 0.125f; v.z *= 0.125f; v.w *= 0.125f;
      *(float4*)&Qs[r][4 * c] = v;
    }
  }
  float M[4], inv[4];
#pragma unroll
  for (int i = 0; i < 4; i++) {
    int gq = q0 + tx + 16 * i;
    if (gq < N_) {
      M[i] = rowmax_g[(size_t)bh * N_ + gq];
      inv[i] = 1.f / rowsum_g[(size_t)bh * N_ + gq];
    } else { M[i] = 0.f; inv[i] = 0.f; }
  }
  for (int n0 = 0; n0 < N_; n0 += 128) {
    __syncthreads();
    {
      const int c = t & 15, r0 = t >> 4;
#pragma unroll
      for (int s = 0; s < 8; s++) {
        int r = r0 + 16 * s;
        int gn = n0 + r;
        float4 v = make_float4(0.f, 0.f, 0.f, 0.f);
        if (gn < N_) v = *(const float4*)&kb[((size_t)bh * N_ + gn) * HD_ + 4 * c];
        *(float4*)&Ksf[r][4 * c] = v;
      }
    }
    __syncthreads();
    float l[4][8];
#pragma unroll
    for (int i = 0; i < 4; i++)
#pragma unroll
      for (int j = 0; j < 8; j++) l[i][j] = 0.f;
#pragma unroll 2
    for (int d4 = 0; d4 < 16; d4++) {
      float4 a4[4], b4[8];
#pragma unroll
      for (int i = 0; i < 4; i++) a4[i] = *(const float4*)&Qs[tx + 16 * i][4 * d4];
#pragma unroll
      for (int j = 0; j < 8; j++) b4[j] = *(const float4*)&Ksf[ty + 16 * j][4 * d4];
#pragma unroll
      for (int i = 0; i < 4; i++)
#pragma unroll
        for (int j = 0; j < 8; j++) fma4(a4[i], b4[j], l[i][j]);
    }
#pragma unroll
    for (int i = 0; i < 4; i++) {
      int gq = q0 + tx + 16 * i;
#pragma unroll
      for (int j = 0; j < 8; j++) {
        bool valid = (gq < N_) && (n0 + ty + 16 * j < N_);
        if (MODE == 0) {
          unsigned bin = 0xFFFFu;
          if (valid) {
            float e = expf(l[i][j] - M[i]);
            float v = e * inv[i];
            bin = __float_as_uint(v) >> 20;
          }
          unsigned lead = (unsigned)__builtin_amdgcn_readfirstlane((int)bin);
          unsigned long long mm = __ballot(bin == lead);
          if (bin == lead) {
            if (lead != 0xFFFFu && (t & 63) == (__ffsll((unsigned long long)mm) - 1))
              atomicAdd(&hloc[lead], (unsigned)__popcll(mm));
          } else if (bin != 0xFFFFu) {
            atomicAdd(&hloc[bin], 1u);
          }
        } else if (valid) {
          float e = expf(l[i][j] - M[i]);
          float v = e * inv[i];
          unsigned bits = __float_as_uint(v);
          if (MODE == 1) {
            if ((bits >> 20) == pf) atomicAdd(&hloc[(bits >> 8) & 0xFFFu], 1u);
          } else {
            if ((bits >> 8) == pf) atomicAdd(&hloc[bits & 0xFFu], 1u);
          }
        }
      }
    }
  }
  __syncthreads();
  for (int i = t; i < HB; i += 256)
    if (hloc[i]) atomicAdd(&hist_out[(size_t)bh * HB + i], hloc[i]);
}

// ------------------------------------------------------ radix-select levels
__global__ __launch_bounds__(64) void select_level(
    const unsigned* __restrict__ hist, int nbins,
    const unsigned* __restrict__ krem_in, const unsigned* __restrict__ pfx_in,
    unsigned* __restrict__ krem_out, unsigned* __restrict__ pfx_out, int shift) {
  const int bh = blockIdx.x;
  const int l = threadIdx.x;
  const int seg = nbins / 64;
  const unsigned krem = krem_in ? krem_in[bh] : KIDX_;
  const unsigned* hb = hist + (size_t)bh * nbins;
  __shared__ unsigned ps[64];
  unsigned psum = 0;
  int hi = nbins - 1 - l * seg;
  for (int i = 0; i < seg; i++) psum += hb[hi - i];
  ps[l] = psum;
  __syncthreads();
  if (l == 0) {
    unsigned cum = 0, before = 0;
    int bin = 0;
    for (int j = 0; j < 64; j++) {
      if (cum + ps[j] > krem) {
        unsigned c = cum;
        int hj = nbins - 1 - j * seg;
        for (int i = 0; i < seg; i++) {
          unsigned cnt = hb[hj - i];
          if (c + cnt > krem) { bin = hj - i; before = c; break; }
          c += cnt;
        }
        break;
      }
      cum += ps[j];
    }
    unsigned p = pfx_in ? pfx_in[bh] : 0u;
    pfx_out[bh] = (p << shift) | (unsigned)bin;
    krem_out[bh] = krem - before;
  }
}

// ------------------------------------------------- token ranking (stable)
__global__ __launch_bounds__(576) void rank_kernel(
    const float* __restrict__ ldiag, const float* __restrict__ rowmax_g,
    const float* __restrict__ rowsum_g, const unsigned* __restrict__ sigbits,
    int* __restrict__ kept) {
  const int b = blockIdx.x;
  const int i = threadIdx.x;  // token i+1
  __shared__ float sc[576];
  float s = 0.f;
  for (int h = 0; h < H_; h++) {
    int bh = b * H_ + h;
    float l = ldiag[(size_t)bh * N_ + (i + 1)];
    float M = rowmax_g[(size_t)bh * N_ + (i + 1)];
    float inv = 1.f / rowsum_g[(size_t)bh * N_ + (i + 1)];
    float e = expf(l - M);
    float v = e * inv;   // bit-identical to hist/AV computation
    float sg = __uint_as_float(sigbits[bh]);
    if (v >= sg) s = fmaxf(s, v);
  }
  sc[i] = s;
  __syncthreads();
  int r = 0;
  for (int j = 0; j < 576; j++) {
    float sj = sc[j];
    if (sj > s || (sj == s && j < i)) r++;
  }
  if (r < KK_ - 1) kept[b * KK_ + r + 1] = i + 1;
  if (i == 0) kept[b * KK_] = 0;
}

// ------------------------------------------------------ gather x_original
__global__ __launch_bounds__(256) void gather_x(
    const float* __restrict__ xo, const int* __restrict__ kept,
    float* __restrict__ out2) {
  const int bp = blockIdx.x;
  const int b = bp / KK_, p = bp % KK_;
  const int src = kept[b * KK_ + p];
  const float* s = xo + ((size_t)b * N_ + src) * C_;
  float* d = out2 + (size_t)bp * C_;
  for (int c = threadIdx.x; c < C_; c += 256) d[c] = s[c];
}

// ------------------------------------------- AV (QK recompute #5 + PV)
// 64 kept rows/block; per 64-col tile: QK (4x4, cols 4ty+j) -> mask -> P
// overlays K -> PV (4x4, out cols 4ty+j contiguous -> float4 stores).
__global__ __launch_bounds__(256) void av_kernel(
    const float* __restrict__ qb, const float* __restrict__ kb,
    const float* __restrict__ vb, const int* __restrict__ kept,
    const float* __restrict__ rowmax_g, const float* __restrict__ rowsum_g,
    const unsigned* __restrict__ sigbits, float* __restrict__ out1) {
  __shared__ __align__(16) float Qs[64][68];
  __shared__ __align__(16) float Ksf[64][68];   // K, then P overlay
  __shared__ __align__(16) float Vs[64][68];
  __shared__ int ridx[64];
  __shared__ float Ml[64], Il[64];
  const int bh = blockIdx.x;
  const int p0 = blockIdx.y * 64;
  const int b = bh / H_, h = bh % H_;
  const float sigma = __uint_as_float(sigbits[bh]);
  const int t = threadIdx.x;
  const int tx = t & 15, ty = t >> 4;
  if (t < 64) {
    int pp = p0 + t;
    int r = (pp < KK_) ? kept[b * KK_ + pp] : 0;
    ridx[t] = r;
    Ml[t] = rowmax_g[(size_t)bh * N_ + r];
    Il[t] = 1.f / rowsum_g[(size_t)bh * N_ + r];
  }
  __syncthreads();
  {
    const int c = t & 15, r0 = t >> 4;
#pragma unroll
    for (int s = 0; s < 4; s++) {
      int r = r0 + 16 * s;
      int gq = ridx[r];
      float4 v = *(const float4*)&qb[((size_t)bh * N_ + gq) * HD_ + 4 * c];
      v.x *= 0.125f; v.y *= 0.125f; v.z *= 0.125f; v.w *= 0.125f;
      *(float4*)&Qs[r][4 * c] = v;
    }
  }
  float M[4], inv[4];
#pragma unroll
  for (int i = 0; i < 4; i++) { int row = tx + 16 * i; M[i] = Ml[row]; inv[i] = Il[row]; }
  float acc[4][4] = {};
  for (int n0 = 0; n0 < N_; n0 += 64) {
    __syncthreads();
    {
      const int c = t & 15, r0 = t >> 4;
#pragma unroll
      for (int s = 0; s < 4; s++) {
        int r = r0 + 16 * s;
        int gn = n0 + r;
        float4 kv = make_float4(0.f, 0.f, 0.f, 0.f);
        float4 vv = make_float4(0.f, 0.f, 0.f, 0.f);
        if (gn < N_) {
          kv = *(const float4*)&kb[((size_t)bh * N_ + gn) * HD_ + 4 * c];
          vv = *(const float4*)&vb[((size_t)bh * N_ + gn) * HD_ + 4 * c];
        }
        *(float4*)&Ksf[r][4 * c] = kv;
        *(float4*)&Vs[r][4 * c] = vv;
      }
    }
    __syncthreads();
    float l[4][4];
#pragma unroll
    for (int i = 0; i < 4; i++)
#pragma unroll
      for (int j = 0; j < 4; j++) l[i][j] = 0.f;
#pragma unroll 4
    for (int d4 = 0; d4 < 16; d4++) {
      float4 a4[4], b4[4];
#pragma unroll
      for (int i = 0; i < 4; i++) a4[i] = *(const float4*)&Qs[tx + 16 * i][4 * d4];
#pragma unroll
      for (int j = 0; j < 4; j++) b4[j] = *(const float4*)&Ksf[4 * ty + j][4 * d4];
#pragma unroll
      for (int i = 0; i < 4; i++)
#pragma unroll
        for (int j = 0; j < 4; j++) fma4(a4[i], b4[j], l[i][j]);
    }
    __syncthreads();   // QK done -> overlay P on Ksf
#pragma unroll
    for (int i = 0; i < 4; i++) {
      float4 pv4;
      float* pp = (float*)&pv4;
#pragma unroll
      for (int j = 0; j < 4; j++) {
        float e = expf(l[i][j] - M[i]);
        float v = e * inv[i];
        pp[j] = (v >= sigma) ? v : 0.f;   // padded cols harmless: V=0
      }
      *(float4*)&Ksf[tx + 16 * i][4 * ty] = pv4;
    }
    __syncthreads();
#pragma unroll 4
    for (int nb = 0; nb < 16; nb++) {
      float4 pa4[4];
#pragma unroll
      for (int i = 0; i < 4; i++) pa4[i] = *(const float4*)&Ksf[tx + 16 * i][4 * nb];
#pragma unroll
      for (int e = 0; e < 4; e++) {
        float4 vv4 = *(const float4*)&Vs[4 * nb + e][4 * ty];
        const float* pa = (const float*)&pa4[0];
#pragma unroll
        for (int i = 0; i < 4; i++) {
          float pvv = ((const float*)&pa4[i])[e];
          acc[i][0] = __builtin_fmaf(pvv, vv4.x, acc[i][0]);
          acc[i][1] = __builtin_fmaf(pvv, vv4.y, acc[i][1]);
          acc[i][2] = __builtin_fmaf(pvv, vv4.z, acc[i][2]);
          acc[i][3] = __builtin_fmaf(pvv, vv4.w, acc[i][3]);
        }
        (void)pa;
      }
    }
  }
#pragma unroll
  for (int i = 0; i < 4; i++) {
    int pp = p0 + tx + 16 * i;
    if (pp >= KK_) continue;
    float4 o = make_float4(acc[i][0], acc[i][1], acc[i][2], acc[i][3]);
    *(float4*)&out1[((size_t)(b * KK_ + pp)) * C_ + h * HD_ + 4 * ty] = o;
  }
}

// ------------------------------------------------------------ proj GEMM
__global__ __launch_bounds__(256) void proj_gemm(
    const float* __restrict__ Xi, const float* __restrict__ W,
    const float* __restrict__ bias, float* __restrict__ out) {
  __shared__ __align__(16) float Xs[64][68];
  __shared__ __align__(16) float Ws2[128][68];
  const int m0 = blockIdx.x * 64;
  const int n0 = blockIdx.y * 128;
  const int t = threadIdx.x;
  const int tx = t & 15, ty = t >> 4;
  float acc[4][8] = {};
  for (int k0 = 0; k0 < 768; k0 += 64) {
    __syncthreads();
    {
      const int c = t & 15, r0 = t >> 4;
#pragma unroll
      for (int s = 0; s < 4; s++) {
        int r = r0 + 16 * s;
        float4 v = *(const float4*)&Xi[(size_t)(m0 + r) * 768 + k0 + 4 * c];
        *(float4*)&Xs[r][4 * c] = v;
      }
#pragma unroll
      for (int s = 0; s < 8; s++) {
        int r = r0 + 16 * s;
        float4 v = *(const float4*)&W[(size_t)(n0 + r) * 768 + k0 + 4 * c];
        *(float4*)&Ws2[r][4 * c] = v;
      }
    }
    __syncthreads();
#pragma unroll 2
    for (int d4 = 0; d4 < 16; d4++) {
      float4 a4[4], b4[8];
#pragma unroll
      for (int i = 0; i < 4; i++) a4[i] = *(const float4*)&Xs[tx + 16 * i][4 * d4];
#pragma unroll
      for (int j = 0; j < 8; j++) b4[j] = *(const float4*)&Ws2[ty + 16 * j][4 * d4];
#pragma unroll
      for (int i = 0; i < 4; i++)
#pragma unroll
        for (int j = 0; j < 8; j++) fma4(a4[i], b4[j], acc[i][j]);
    }
  }
  for (int i = 0; i < 4; i++) {
    int gm = m0 + tx + 16 * i;   // M2 = 8320 = 130*64, no guard
    for (int j = 0; j < 8; j++) {
      int gn = n0 + ty + 16 * j;
      out[(size_t)gm * C_ + gn] = acc[i][j] + bias[gn];
    }
  }
}

// ---------------------------------------------------------------- launcher
extern "C" void kernel_launch(void* const* d_in, const int* in_sizes, int n_in,
                              void* d_out, int out_size, void* d_ws, size_t ws_size,
                              hipStream_t stream) {
  (void)in_sizes; (void)n_in; (void)out_size; (void)ws_size;
  const float* x    = (const float*)d_in[0];
  const float* xo   = (const float*)d_in[1];
  const float* qkvw = (const float*)d_in[2];
  const float* pw   = (const float*)d_in[3];
  const float* pb   = (const float*)d_in[4];

  char* ws = (char*)d_ws;
  size_t off = 0;
  auto alloc = [&](size_t bytes) -> char* {
    char* p = ws + off;
    off += (bytes + 255) & ~(size_t)255;
    return p;
  };
  const size_t szQ    = (size_t)BH_ * N_ * HD_ * 4;   // 28.4 MB
  const size_t szOut1 = (size_t)M2_ * C_ * 4;         // 25.6 MB
  const size_t szRow  = (size_t)BH_ * N_ * 4;         // 443 KB
  const size_t szH12  = (size_t)BH_ * 4096 * 4;       // 3.1 MB
  const size_t szH3   = (size_t)BH_ * 256 * 4;

  float* qb     = (float*)alloc(szQ);
  float* kb     = (float*)alloc(szQ);
  float* vb     = (float*)alloc(szQ);
  float* out1   = (float*)alloc(szOut1);
  float* ldiag  = (float*)alloc(szRow);
  float* rowmax = (float*)alloc(szRow);
  float* rowsum = (float*)alloc(szRow);
  unsigned* hist1 = (unsigned*)alloc(szH12);
  unsigned* hist2 = (unsigned*)alloc(szH12);
  unsigned* hist3 = (unsigned*)alloc(szH3);
  unsigned* pfx1  = (unsigned*)alloc(BH_ * 4);
  unsigned* krem1 = (unsigned*)alloc(BH_ * 4);
  unsigned* pfx2  = (unsigned*)alloc(BH_ * 4);
  unsigned* krem2 = (unsigned*)alloc(BH_ * 4);
  unsigned* pfx3  = (unsigned*)alloc(BH_ * 4);
  unsigned* krem3 = (unsigned*)alloc(BH_ * 4);
  int* kept       = (int*)alloc((size_t)B_ * KK_ * 4);

  hipMemsetAsync(hist1, 0, szH12, stream);
  hipMemsetAsync(hist2, 0, szH12, stream);
  hipMemsetAsync(hist3, 0, szH3, stream);

  qkv_gemm<<<dim3(145, 18), 256, 0, stream>>>(x, qkvw, qb, kb, vb);
  attn_stats<<<dim3(BH_, 10), 256, 0, stream>>>(qb, kb, rowmax, rowsum, ldiag);
  hist_pass<0><<<dim3(BH_, 10), 256, 0, stream>>>(qb, kb, rowmax, rowsum, nullptr, hist1);
  select_level<<<BH_, 64, 0, stream>>>(hist1, 4096, nullptr, nullptr, krem1, pfx1, 12);
  hist_pass<1><<<dim3(BH_, 10), 256, 0, stream>>>(qb, kb, rowmax, rowsum, pfx1, hist2);
  select_level<<<BH_, 64, 0, stream>>>(hist2, 4096, krem1, pfx1, krem2, pfx2, 12);
  hist_pass<2><<<dim3(BH_, 10), 256, 0, stream>>>(qb, kb, rowmax, rowsum, pfx2, hist3);
  select_level<<<BH_, 64, 0, stream>>>(hist3, 256, krem2, pfx2, krem3, pfx3, 8);
  rank_kernel<<<B_, 576, 0, stream>>>(ldiag, rowmax, rowsum, pfx3, kept);

  float* outp = (float*)d_out;
  gather_x<<<M2_, 256, 0, stream>>>(xo, kept, outp + (size_t)M2_ * C_);
  av_kernel<<<dim3(BH_, 9), 256, 0, stream>>>(qb, kb, vb, kept, rowmax, rowsum, pfx3, out1);
  proj_gemm<<<dim3(130, 6), 256, 0, stream>>>(out1, pw, pb, outp);
}